// Round 4
// baseline (48.645 us; speedup 1.0000x reference)
//
#include <hip/hip_runtime.h>
#include <hip/hip_cooperative_groups.h>
#include <math.h>

namespace cg = cooperative_groups;

#define N_NEURONS 100000
#define N_PERCEPTORS 1024
#define N_MOTORS 256
#define N_CONNECTIONS 32
#define N_ACTIONS 16
#define BATCH 64
#define N_OUT (N_NEURONS - N_PERCEPTORS)   // 98976
#define O_BASE (N_OUT - N_MOTORS)          // 98720

// Cooperative single kernel, 256 blocks x 512 threads (1 block/CU).
// Phase 1 (all 256 blocks): block = (b = bid>>2, quarter qt = bid&3).
//   Thread t: local neuron nl = t>>3 (64 per block), conn group g = t&7
//   (4 connections each). 4 scattered x-gathers + dot4 -> LDS reduce ->
//   sigmoid -> nm[b][qt*64+nl] in d_ws.
// grid.sync()
// Phase 2 (first 64 blocks): block = batch row b. 256 threads compute
//   q[b][a] = b_motor[a] + sum_m nm[b][m] * w_motor[a][m].
__global__ __launch_bounds__(512) void brain_coop_kernel(
    const float* __restrict__ x,
    const int*   __restrict__ idx,
    const float* __restrict__ w_sparse,
    const float* __restrict__ b_sparse,
    const float* __restrict__ w_motor,
    const float* __restrict__ b_motor,
    float* __restrict__ q,
    float* __restrict__ nm) {
  const int bid = blockIdx.x;    // 0..255
  const int b   = bid >> 2;      // batch row
  const int qt  = bid & 3;       // neuron quarter
  const int t   = threadIdx.x;   // 0..511
  const int nl  = t >> 3;        // 0..63 local neuron
  const int g   = t & 7;         // connection group (4 conns)
  const int o   = O_BASE + qt * 64 + nl;

  // 16B idx + 16B w per thread, contiguous across the wave.
  const long base = (long)o * N_CONNECTIONS + g * 4;
  const int4   iv = *(const int4*)  (idx      + base);
  const float4 wv = *(const float4*)(w_sparse + base);

  const float* xb = x + (long)b * N_NEURONS;
  const float acc = xb[iv.x]*wv.x + xb[iv.y]*wv.y
                  + xb[iv.z]*wv.z + xb[iv.w]*wv.w;

  __shared__ float part[512];
  part[t] = acc;
  __syncthreads();

  if (t < 64) {
    const float* p = part + t * 8;
    const float pre = ((p[0]+p[1]) + (p[2]+p[3]))
                    + ((p[4]+p[5]) + (p[6]+p[7]))
                    + b_sparse[O_BASE + qt * 64 + t];
    nm[b * N_MOTORS + qt * 64 + t] = 1.f / (1.f + __expf(-pre));
  }

  cg::this_grid().sync();

  // Phase 2: first 64 blocks finish the 256->16 matvec for their row.
  __shared__ float pq[256];
  if (bid < BATCH) {
    if (t < 256) {
      const int a     = t & 15;
      const int chunk = t >> 4;
      const float* sm = nm      + bid * N_MOTORS + chunk * 16;
      const float* wm = w_motor + a   * N_MOTORS + chunk * 16;
      float accq = 0.f;
#pragma unroll
      for (int i = 0; i < 16; ++i) accq += sm[i] * wm[i];
      pq[t] = accq;
    }
    __syncthreads();
    if (t < N_ACTIONS) {
      float sum = b_motor[t];
#pragma unroll
      for (int ch = 0; ch < 16; ++ch) sum += pq[ch * 16 + t];
      q[bid * N_ACTIONS + t] = sum;
    }
  }
}

extern "C" void kernel_launch(void* const* d_in, const int* in_sizes, int n_in,
                              void* d_out, int out_size, void* d_ws, size_t ws_size,
                              hipStream_t stream) {
  const float* x        = (const float*)d_in[0];
  const int*   idx      = (const int*)  d_in[1];
  const float* w_sparse = (const float*)d_in[2];
  const float* b_sparse = (const float*)d_in[3];
  const float* w_motor  = (const float*)d_in[4];
  const float* b_motor  = (const float*)d_in[5];
  float* q  = (float*)d_out;
  float* nm = (float*)d_ws;   // BATCH * N_MOTORS floats = 64 KB scratch

  void* args[] = { (void*)&x, (void*)&idx, (void*)&w_sparse, (void*)&b_sparse,
                   (void*)&w_motor, (void*)&b_motor, (void*)&q, (void*)&nm };
  hipLaunchCooperativeKernel((void*)brain_coop_kernel,
                             dim3(256), dim3(512), args, 0, stream);
}

// Round 5
// 14.703 us; speedup vs baseline: 3.3084x; 3.3084x over previous
//
#include <hip/hip_runtime.h>
#include <math.h>

#define N_NEURONS 100000
#define N_PERCEPTORS 1024
#define N_MOTORS 256
#define N_CONNECTIONS 32
#define N_ACTIONS 16
#define BATCH 64
#define N_OUT (N_NEURONS - N_PERCEPTORS)   // 98976
#define O_BASE (N_OUT - N_MOTORS)          // 98720

// K1: 256 blocks x 512 threads. Block = (b = bid>>2, quarter qt = bid&3).
// Gathers 64 neurons x 32 connections (2048 lane-loads/block ~= 1 block/CU),
// sigmoid, then this quarter's partial matvec vs w_motor -> ws[b][qt][16].
__global__ __launch_bounds__(512) void gather_partial_kernel(
    const float* __restrict__ x,
    const int*   __restrict__ idx,
    const float* __restrict__ w_sparse,
    const float* __restrict__ b_sparse,
    const float* __restrict__ w_motor,
    float* __restrict__ ws) {
  const int bid = blockIdx.x;    // 0..255
  const int b   = bid >> 2;      // batch row
  const int qt  = bid & 3;       // neuron quarter
  const int t   = threadIdx.x;   // 0..511
  const int nl  = t >> 3;        // 0..63 local neuron
  const int g   = t & 7;         // connection group of 4
  const int o   = O_BASE + qt * 64 + nl;

  // 16B idx + 16B w per thread, contiguous across the block.
  const long base = (long)o * N_CONNECTIONS + g * 4;
  const int4   iv = *(const int4*)  (idx      + base);
  const float4 wv = *(const float4*)(w_sparse + base);

  const float* xb = x + (long)b * N_NEURONS;
  const float acc = xb[iv.x]*wv.x + xb[iv.y]*wv.y
                  + xb[iv.z]*wv.z + xb[iv.w]*wv.w;

  __shared__ float part[512];
  part[t] = acc;
  __syncthreads();

  __shared__ float s_nm[64];
  if (t < 64) {
    const float* p = part + t * 8;
    const float pre = ((p[0]+p[1]) + (p[2]+p[3]))
                    + ((p[4]+p[5]) + (p[6]+p[7]))
                    + b_sparse[O_BASE + qt * 64 + t];
    s_nm[t] = 1.f / (1.f + __expf(-pre));
  }
  __syncthreads();

  // Partial matvec: this quarter's 64 neurons x 16 actions.
  // t < 256: a = t&15, grp = t>>4 owns local m = grp*4 .. grp*4+3.
  __shared__ float pq[16][17];   // pq[a][grp], padded
  if (t < 256) {
    const int a   = t & 15;
    const int grp = t >> 4;
    const float* wm = w_motor + a * N_MOTORS + qt * 64 + grp * 4;
    const float* sm = s_nm + grp * 4;
    pq[a][grp] = sm[0]*wm[0] + sm[1]*wm[1] + sm[2]*wm[2] + sm[3]*wm[3];
  }
  __syncthreads();

  if (t < N_ACTIONS) {
    float sum = 0.f;
#pragma unroll
    for (int grp = 0; grp < 16; ++grp) sum += pq[t][grp];
    ws[(b * 4 + qt) * N_ACTIONS + t] = sum;
  }
}

// K2: 1 block x 1024 threads. t = b*16 + a.
// q[b][a] = b_motor[a] + sum_qt ws[b][qt][a]
__global__ __launch_bounds__(1024) void finish_kernel(
    const float* __restrict__ ws,
    const float* __restrict__ b_motor,
    float* __restrict__ q) {
  const int t = threadIdx.x;   // 0..1023
  const int b = t >> 4;
  const int a = t & 15;
  const float* w = ws + b * 4 * N_ACTIONS + a;
  q[t] = b_motor[a] + ((w[0] + w[N_ACTIONS]) + (w[2*N_ACTIONS] + w[3*N_ACTIONS]));
}

extern "C" void kernel_launch(void* const* d_in, const int* in_sizes, int n_in,
                              void* d_out, int out_size, void* d_ws, size_t ws_size,
                              hipStream_t stream) {
  const float* x        = (const float*)d_in[0];
  const int*   idx      = (const int*)  d_in[1];
  const float* w_sparse = (const float*)d_in[2];
  const float* b_sparse = (const float*)d_in[3];
  const float* w_motor  = (const float*)d_in[4];
  const float* b_motor  = (const float*)d_in[5];
  float* q  = (float*)d_out;
  float* ws = (float*)d_ws;   // 64*4*16 floats = 16 KB scratch

  gather_partial_kernel<<<256, 512, 0, stream>>>(x, idx, w_sparse, b_sparse,
                                                 w_motor, ws);
  finish_kernel<<<1, BATCH * N_ACTIONS, 0, stream>>>(ws, b_motor, q);
}

// Round 9
// 14.336 us; speedup vs baseline: 3.3933x; 1.0256x over previous
//
#include <hip/hip_runtime.h>
#include <math.h>

#define N_NEURONS 100000
#define N_PERCEPTORS 1024
#define N_MOTORS 256
#define N_CONNECTIONS 32
#define N_ACTIONS 16
#define BATCH 64
#define N_OUT (N_NEURONS - N_PERCEPTORS)   // 98976
#define O_BASE (N_OUT - N_MOTORS)          // 98720

// Single dispatch, 64 blocks (one per batch row) x 1024 threads (16 waves).
// No cross-block communication (rounds 6-8 proved intra-dispatch cross-block
// dataflow is not coherently possible on this chip without dispatch-level
// overhead exceeding the win).
// Phase 1: thread t owns (neuron nl = t>>2, conn group g = t&3): 8 gathers.
//          32->1 reduce via __shfl_xor over the 4 consecutive lanes of nl.
// Phase 2: matvec q[b][a] = b_motor[a] + sum_m s_nm[m]*w_motor[a][m].
__global__ __launch_bounds__(1024) void brain_fused_kernel(
    const float* __restrict__ x,
    const int*   __restrict__ idx,
    const float* __restrict__ w_sparse,
    const float* __restrict__ b_sparse,
    const float* __restrict__ w_motor,
    const float* __restrict__ b_motor,
    float* __restrict__ q) {
  const int b = blockIdx.x;      // 0..63
  const int t = threadIdx.x;     // 0..1023
  const int nl = t >> 2;         // 0..255 motor neuron (local)
  const int g  = t & 3;          // conn group: connections g*8 .. g*8+7
  const int o  = O_BASE + nl;

  // 32 B idx + 32 B w per thread, contiguous across the block.
  const long base = (long)o * N_CONNECTIONS + g * 8;
  const int4*   ip = (const int4*)  (idx      + base);
  const float4* wp = (const float4*)(w_sparse + base);
  const int4   i0 = ip[0], i1 = ip[1];
  const float4 w0 = wp[0], w1 = wp[1];

  const float* xb = x + (long)b * N_NEURONS;
  float acc;
  {
    const float a0 = xb[i0.x]*w0.x + xb[i0.y]*w0.y
                   + xb[i0.z]*w0.z + xb[i0.w]*w0.w;
    const float a1 = xb[i1.x]*w1.x + xb[i1.y]*w1.y
                   + xb[i1.z]*w1.z + xb[i1.w]*w1.w;
    acc = a0 + a1;
  }
  // Reduce the 4 lanes (same wave, consecutive) holding neuron nl.
  acc += __shfl_xor(acc, 1);
  acc += __shfl_xor(acc, 2);

  __shared__ float s_nm[N_MOTORS];
  if (g == 0) {
    const float pre = acc + b_sparse[o];
    s_nm[nl] = 1.f / (1.f + __expf(-pre));
  }
  __syncthreads();

  // Phase 2: first 256 threads, thread = (chunk = t>>4, a = t&15).
  __shared__ float p[N_MOTORS];   // p[chunk*16 + a]
  if (t < N_MOTORS) {
    const int a     = t & 15;
    const int chunk = t >> 4;
    const float* wm = w_motor + a * N_MOTORS + chunk * 16;
    const float* sm = s_nm + chunk * 16;
    float accq = 0.f;
#pragma unroll
    for (int i = 0; i < 16; ++i) accq += sm[i] * wm[i];
    p[t] = accq;
  }
  __syncthreads();

  if (t < N_ACTIONS) {
    float sum = b_motor[t];
#pragma unroll
    for (int ch = 0; ch < 16; ++ch) sum += p[ch * 16 + t];
    q[b * N_ACTIONS + t] = sum;
  }
}

extern "C" void kernel_launch(void* const* d_in, const int* in_sizes, int n_in,
                              void* d_out, int out_size, void* d_ws, size_t ws_size,
                              hipStream_t stream) {
  const float* x        = (const float*)d_in[0];
  const int*   idx      = (const int*)  d_in[1];
  const float* w_sparse = (const float*)d_in[2];
  const float* b_sparse = (const float*)d_in[3];
  const float* w_motor  = (const float*)d_in[4];
  const float* b_motor  = (const float*)d_in[5];
  float* q = (float*)d_out;

  brain_fused_kernel<<<BATCH, 1024, 0, stream>>>(
      x, idx, w_sparse, b_sparse, w_motor, b_motor, q);
}

// Round 10
// 13.788 us; speedup vs baseline: 3.5280x; 1.0397x over previous
//
#include <hip/hip_runtime.h>
#include <math.h>

#define N_NEURONS 100000
#define N_PERCEPTORS 1024
#define N_MOTORS 256
#define N_CONNECTIONS 32
#define N_ACTIONS 16
#define BATCH 64
#define N_OUT (N_NEURONS - N_PERCEPTORS)   // 98976
#define O_BASE (N_OUT - N_MOTORS)          // 98720

// Single dispatch, 64 blocks (one per batch row) x 512 threads (8 waves).
// R3 structure with the part[512] LDS round-trip replaced by one shfl:
// thread t = 2*nl + h owns neuron nl's half h (16 gathers, int4/float4 x4);
// halves combined via __shfl_xor(acc,1) (consecutive lanes, same wave);
// h==0 lane writes sigmoid -> s_nm. Then the proven 256-thread matvec.
__global__ __launch_bounds__(512) void brain_fused_kernel(
    const float* __restrict__ x,
    const int*   __restrict__ idx,
    const float* __restrict__ w_sparse,
    const float* __restrict__ b_sparse,
    const float* __restrict__ w_motor,
    const float* __restrict__ b_motor,
    float* __restrict__ q) {
  const int b = blockIdx.x;      // 0..63
  const int t = threadIdx.x;     // 0..511
  const int nl = t >> 1;         // 0..255 motor neuron (local)
  const int h  = t & 1;          // half: connections h*16 .. h*16+15
  const int o  = O_BASE + nl;

  // 64 B idx + 64 B w per thread, contiguous across the block.
  const long base = (long)o * N_CONNECTIONS + h * 16;
  const int4*   ip = (const int4*)  (idx      + base);
  const float4* wp = (const float4*)(w_sparse + base);
  const int4   i0 = ip[0], i1 = ip[1], i2 = ip[2], i3 = ip[3];
  const float4 w0 = wp[0], w1 = wp[1], w2 = wp[2], w3 = wp[3];

  const float* xb = x + (long)b * N_NEURONS;
  float acc = 0.f;
  acc += xb[i0.x]*w0.x + xb[i0.y]*w0.y + xb[i0.z]*w0.z + xb[i0.w]*w0.w;
  acc += xb[i1.x]*w1.x + xb[i1.y]*w1.y + xb[i1.z]*w1.z + xb[i1.w]*w1.w;
  acc += xb[i2.x]*w2.x + xb[i2.y]*w2.y + xb[i2.z]*w2.z + xb[i2.w]*w2.w;
  acc += xb[i3.x]*w3.x + xb[i3.y]*w3.y + xb[i3.z]*w3.z + xb[i3.w]*w3.w;

  // Combine the two halves (consecutive lanes, same wave).
  acc += __shfl_xor(acc, 1);

  __shared__ float s_nm[N_MOTORS];
  if (h == 0) {
    const float pre = acc + b_sparse[o];
    s_nm[nl] = 1.f / (1.f + __expf(-pre));
  }
  __syncthreads();

  // Phase 2: first 256 threads, thread = (chunk = t>>4, a = t&15).
  __shared__ float p[N_MOTORS];   // p[chunk*16 + a]
  if (t < N_MOTORS) {
    const int a     = t & 15;
    const int chunk = t >> 4;
    const float* wm = w_motor + a * N_MOTORS + chunk * 16;
    const float* sm = s_nm + chunk * 16;
    float accq = 0.f;
#pragma unroll
    for (int i = 0; i < 16; ++i) accq += sm[i] * wm[i];
    p[t] = accq;
  }
  __syncthreads();

  if (t < N_ACTIONS) {
    float sum = b_motor[t];
#pragma unroll
    for (int ch = 0; ch < 16; ++ch) sum += p[ch * 16 + t];
    q[b * N_ACTIONS + t] = sum;
  }
}

extern "C" void kernel_launch(void* const* d_in, const int* in_sizes, int n_in,
                              void* d_out, int out_size, void* d_ws, size_t ws_size,
                              hipStream_t stream) {
  const float* x        = (const float*)d_in[0];
  const int*   idx      = (const int*)  d_in[1];
  const float* w_sparse = (const float*)d_in[2];
  const float* b_sparse = (const float*)d_in[3];
  const float* w_motor  = (const float*)d_in[4];
  const float* b_motor  = (const float*)d_in[5];
  float* q = (float*)d_out;

  brain_fused_kernel<<<BATCH, 512, 0, stream>>>(
      x, idx, w_sparse, b_sparse, w_motor, b_motor, q);
}

// Round 11
// 11.568 us; speedup vs baseline: 4.2051x; 1.1919x over previous
//
#include <hip/hip_runtime.h>
#include <math.h>

#define N_NEURONS 100000
#define N_PERCEPTORS 1024
#define N_MOTORS 256
#define N_CONNECTIONS 32
#define N_ACTIONS 16
#define BATCH 64
#define N_OUT (N_NEURONS - N_PERCEPTORS)   // 98976
#define O_BASE (N_OUT - N_MOTORS)          // 98720

// Round-3 kernel, resubmitted verbatim (best measured: 11.7 us).
// Fully fused: block = batch row b (64 blocks), 512 threads = 8 waves.
// Phase 1: thread t owns (neuron m = t>>1, half h = t&1): 16 gathers+FMA.
// Phase 2: combine halves + bias + sigmoid -> s_nm[256] in LDS.
// Phase 3: q[b][a] = b_motor[a] + sum_m s_nm[m]*w_motor[a][m] via 256 threads.
__global__ __launch_bounds__(512) void brain_fused_kernel(
    const float* __restrict__ x,
    const int*   __restrict__ idx,
    const float* __restrict__ w_sparse,
    const float* __restrict__ b_sparse,
    const float* __restrict__ w_motor,
    const float* __restrict__ b_motor,
    float* __restrict__ q) {
  const int b = blockIdx.x;      // 0..63
  const int t = threadIdx.x;     // 0..511
  const int m = t >> 1;          // 0..255 motor neuron
  const int h = t & 1;           // half: connections h*16 .. h*16+15
  const int o = O_BASE + m;

  // idx/w for this thread's 16 connections: contiguous 64 B, fully coalesced.
  const long base = (long)o * N_CONNECTIONS + h * 16;
  const int4*   ip = (const int4*)  (idx      + base);
  const float4* wp = (const float4*)(w_sparse + base);
  int4   i0 = ip[0], i1 = ip[1], i2 = ip[2], i3 = ip[3];
  float4 w0 = wp[0], w1 = wp[1], w2 = wp[2], w3 = wp[3];

  const float* xb = x + (long)b * N_NEURONS;
  float acc = 0.f;
  acc += xb[i0.x]*w0.x + xb[i0.y]*w0.y + xb[i0.z]*w0.z + xb[i0.w]*w0.w;
  acc += xb[i1.x]*w1.x + xb[i1.y]*w1.y + xb[i1.z]*w1.z + xb[i1.w]*w1.w;
  acc += xb[i2.x]*w2.x + xb[i2.y]*w2.y + xb[i2.z]*w2.z + xb[i2.w]*w2.w;
  acc += xb[i3.x]*w3.x + xb[i3.y]*w3.y + xb[i3.z]*w3.z + xb[i3.w]*w3.w;

  __shared__ float part[512];
  part[t] = acc;
  __syncthreads();

  __shared__ float s_nm[N_MOTORS];
  if (t < N_MOTORS) {
    const float pre = part[2*t] + part[2*t + 1] + b_sparse[O_BASE + t];
    s_nm[t] = 1.f / (1.f + __expf(-pre));
  }
  __syncthreads();

  // Phase 3: 256 threads, thread = (chunk = t>>4, a = t&15) covers m-range.
  __shared__ float p[N_MOTORS];   // p[chunk*16 + a]
  if (t < N_MOTORS) {
    const int a     = t & 15;
    const int chunk = t >> 4;
    const float* wm = w_motor + a * N_MOTORS + chunk * 16;
    const float* sm = s_nm + chunk * 16;
    float accq = 0.f;
#pragma unroll
    for (int i = 0; i < 16; ++i) accq += sm[i] * wm[i];
    p[t] = accq;
  }
  __syncthreads();

  if (t < N_ACTIONS) {
    float sum = b_motor[t];
#pragma unroll
    for (int ch = 0; ch < 16; ++ch) sum += p[ch * 16 + t];
    q[b * N_ACTIONS + t] = sum;
  }
}

extern "C" void kernel_launch(void* const* d_in, const int* in_sizes, int n_in,
                              void* d_out, int out_size, void* d_ws, size_t ws_size,
                              hipStream_t stream) {
  const float* x        = (const float*)d_in[0];
  const int*   idx      = (const int*)  d_in[1];
  const float* w_sparse = (const float*)d_in[2];
  const float* b_sparse = (const float*)d_in[3];
  const float* w_motor  = (const float*)d_in[4];
  const float* b_motor  = (const float*)d_in[5];
  float* q = (float*)d_out;

  brain_fused_kernel<<<BATCH, 512, 0, stream>>>(
      x, idx, w_sparse, b_sparse, w_motor, b_motor, q);
}